// Round 6
// baseline (72.766 us; speedup 1.0000x reference)
//
#include <hip/hip_runtime.h>
#include <hip/hip_bf16.h>
#include <math.h>

#define HW 16384
#define NC 64
#define NB 16
#define CH 32               // k-chunks per batch -> 512 blocks of 128 threads
#define KPB (HW / CH)       // 512 k per block
#define KPW (KPB / 2)       // 256 k per wave (2 waves/block)
#define NST (KPW / 32)      // 8 k-steps of 32 per wave

// ws layout (floats):
//   [0,1024)    S_v    [1024,2048) S_t    [2048,3072) U_t
//   [3072,4096) gw
//   [4096, 4096+npart*65536)  J_raw partial copies (npart x NB x 64 x 64)

typedef __attribute__((ext_vector_type(8))) short bf16x8;
typedef __attribute__((ext_vector_type(4))) float f32x4;

__device__ inline short bfs(float x) {
  union { __hip_bfloat16 h; short s; } u;
  u.h = __float2bfloat16(x);            // RNE
  return u.s;
}

__device__ inline float wave_reduce_sum(float v) {
#pragma unroll
  for (int o = 32; o > 0; o >>= 1) v += __shfl_down(v, o, 64);
  return v;
}

#if __has_builtin(__builtin_amdgcn_global_load_lds)
__device__ inline void gload16(const float* g, float* l) {
  __builtin_amdgcn_global_load_lds(
      (const __attribute__((address_space(1))) void*)g,
      (__attribute__((address_space(3))) void*)l, 16, 0, 0);
}
#else
__device__ inline void gload16(const float* g, float* l) {
  *(f32x4*)(l + (threadIdx.x & 63) * 4) = *(const f32x4*)g;
}
#endif

// Tile: [64 rows][32 k] f32, row stride 128 B = 8 x 16B slots.
// Storage slot s' holds logical slot s = s' ^ (row&7); achieved by
// pre-swizzling the GLOBAL source column (linear LDS dest for gload_lds).
// One k-step = 16 gload16 (8 per tensor), 16 KB per wave.

__device__ __forceinline__ void issue_step(const float* vg, const float* tg,
                                           int m, float* Vd, float* Td) {
#pragma unroll
  for (int i = 0; i < 8; ++i) {
    gload16(vg + (size_t)i * 8 * HW + m * 32, Vd + i * 256);
    gload16(tg + (size_t)i * 8 * HW + m * 32, Td + i * 256);
  }
}

__device__ __forceinline__ void step_compute(const f32x4 av0[4], const f32x4 av1[4],
                                             const f32x4 bv0[4], const f32x4 bv1[4],
                                             f32x4 acc[4][4],
                                             float sv[4], float st[4], float ut[4]) {
  bf16x8 fa[4], fb[4];
#pragma unroll
  for (int f = 0; f < 4; ++f) {
    float e0 = __expf(av0[f][0]), e1 = __expf(av0[f][1]),
          e2 = __expf(av0[f][2]), e3 = __expf(av0[f][3]),
          e4 = __expf(av1[f][0]), e5 = __expf(av1[f][1]),
          e6 = __expf(av1[f][2]), e7 = __expf(av1[f][3]);
    sv[f] += ((e0 + e1) + (e2 + e3)) + ((e4 + e5) + (e6 + e7));
    fa[f][0] = bfs(e0); fa[f][1] = bfs(e1); fa[f][2] = bfs(e2); fa[f][3] = bfs(e3);
    fa[f][4] = bfs(e4); fa[f][5] = bfs(e5); fa[f][6] = bfs(e6); fa[f][7] = bfs(e7);
  }
#pragma unroll
  for (int f = 0; f < 4; ++f) {
    float e0 = __expf(bv0[f][0]), e1 = __expf(bv0[f][1]),
          e2 = __expf(bv0[f][2]), e3 = __expf(bv0[f][3]),
          e4 = __expf(bv1[f][0]), e5 = __expf(bv1[f][1]),
          e6 = __expf(bv1[f][2]), e7 = __expf(bv1[f][3]);
    st[f] += ((e0 + e1) + (e2 + e3)) + ((e4 + e5) + (e6 + e7));
    ut[f] += ((e0 * bv0[f][0] + e1 * bv0[f][1]) + (e2 * bv0[f][2] + e3 * bv0[f][3]))
           + ((e4 * bv1[f][0] + e5 * bv1[f][1]) + (e6 * bv1[f][2] + e7 * bv1[f][3]));
    fb[f][0] = bfs(e0); fb[f][1] = bfs(e1); fb[f][2] = bfs(e2); fb[f][3] = bfs(e3);
    fb[f][4] = bfs(e4); fb[f][5] = bfs(e5); fb[f][6] = bfs(e6); fb[f][7] = bfs(e7);
  }
#pragma unroll
  for (int fi = 0; fi < 4; ++fi)
#pragma unroll
    for (int fj = 0; fj < 4; ++fj)
      acc[fi][fj] = __builtin_amdgcn_mfma_f32_16x16x32_bf16(fa[fi], fb[fj],
                                                            acc[fi][fj], 0, 0, 0);
}

// One k-step: wait (counted!), frag-read current set, issue step m+2 into it,
// compute. VMC is a string literal: "16" in steady state, "0" only at the end.
#define KSTEP(Vc, Tc, VMC, DO_ISSUE)                                   \
  do {                                                                  \
    asm volatile("s_waitcnt vmcnt(" VMC ")" ::: "memory");              \
    __builtin_amdgcn_sched_barrier(0);                                  \
    f32x4 av0[4], av1[4], bv0[4], bv1[4];                               \
    _Pragma("unroll") for (int f = 0; f < 4; ++f) {                     \
      av0[f] = *(const f32x4*)(Vc + f * 512 + offF0);                   \
      av1[f] = *(const f32x4*)(Vc + f * 512 + offF1);                   \
      bv0[f] = *(const f32x4*)(Tc + f * 512 + offF0);                   \
      bv1[f] = *(const f32x4*)(Tc + f * 512 + offF1);                   \
    }                                                                   \
    asm volatile("s_waitcnt lgkmcnt(0)" ::: "memory");                  \
    __builtin_amdgcn_sched_barrier(0);                                  \
    DO_ISSUE;                                                           \
    step_compute(av0, av1, bv0, bv1, acc, sv, st, ut);                  \
  } while (0)

__global__ __launch_bounds__(128) void joint_db(const float* __restrict__ vis,
                                                const float* __restrict__ text,
                                                float* __restrict__ ws,
                                                int jmask) {
  const int b = blockIdx.x / CH;
  const int chunk = blockIdx.x % CH;
  const int t = threadIdx.x;
  const int w = t >> 6;                 // wave 0..1
  const int l = t & 63;

  __shared__ float smem[2 * 8192];      // 64 KB: wave w -> 4 tile-buffers
  __shared__ float sbuf[2][192];

  float* VA = smem + w * 8192;          // set A: k-step even
  float* TA = VA + 2048;
  float* VB = VA + 4096;                // set B: k-step odd
  float* TB = VA + 6144;

  const int kw = chunk * KPB + w * KPW;
  const int srow = l >> 3;                      // source row-in-group 0..7
  const int scol = ((l & 7) ^ srow) << 2;       // pre-swizzled float col
  const float* vg = vis  + ((size_t)b * NC + srow) * HW + kw + scol;
  const float* tg = text + ((size_t)b * NC + srow) * HW + kw + scol;

  // fragment read offsets (A-row m = l&15, k = (l>>4)*8 + [0,8))
  const int xorv = l & 7;
  const int s0 = (l >> 4) << 1;
  const int offF0 = (l & 15) * 32 + ((s0 ^ xorv) << 2);
  const int offF1 = (l & 15) * 32 + (((s0 | 1) ^ xorv) << 2);

  f32x4 acc[4][4];
#pragma unroll
  for (int i = 0; i < 4; ++i)
#pragma unroll
    for (int j = 0; j < 4; ++j) acc[i][j] = (f32x4){0.f, 0.f, 0.f, 0.f};
  float sv[4] = {0.f, 0.f, 0.f, 0.f};
  float st[4] = {0.f, 0.f, 0.f, 0.f};
  float ut[4] = {0.f, 0.f, 0.f, 0.f};

  // prologue: two steps in flight
  issue_step(vg, tg, 0, VA, TA);
  issue_step(vg, tg, 1, VB, TB);

  // 8 k-steps, fully unrolled; vmcnt counted (16 = next step stays in flight)
  KSTEP(VA, TA, "16", issue_step(vg, tg, 2, VA, TA));   // m=0
  KSTEP(VB, TB, "16", issue_step(vg, tg, 3, VB, TB));   // m=1
  KSTEP(VA, TA, "16", issue_step(vg, tg, 4, VA, TA));   // m=2
  KSTEP(VB, TB, "16", issue_step(vg, tg, 5, VB, TB));   // m=3
  KSTEP(VA, TA, "16", issue_step(vg, tg, 6, VA, TA));   // m=4
  KSTEP(VB, TB, "16", issue_step(vg, tg, 7, VB, TB));   // m=5
  KSTEP(VA, TA, "16", );                                 // m=6
  KSTEP(VB, TB, "0",  );                                 // m=7

  // ---- stats: lanes l, l+16, l+32, l+48 hold same rows, disjoint k ----
#pragma unroll
  for (int f = 0; f < 4; ++f) {
    sv[f] += __shfl_xor(sv[f], 16, 64); sv[f] += __shfl_xor(sv[f], 32, 64);
    st[f] += __shfl_xor(st[f], 16, 64); st[f] += __shfl_xor(st[f], 32, 64);
    ut[f] += __shfl_xor(ut[f], 16, 64); ut[f] += __shfl_xor(ut[f], 32, 64);
  }
  if (l < 16) {
#pragma unroll
    for (int f = 0; f < 4; ++f) {
      sbuf[w][      16 * f + l] = sv[f];
      sbuf[w][ 64 + 16 * f + l] = st[f];
      sbuf[w][128 + 16 * f + l] = ut[f];
    }
  }

  // ---- J: write acc into this wave's region (reuse tile LDS) ----
  float* red = smem + w * 8192;
  const int m16 = l & 15, q4 = (l >> 4) * 4;
  // C/D layout: col = l&15, row = (l>>4)*4 + reg (verified R2/R4/R5)
#pragma unroll
  for (int fi = 0; fi < 4; ++fi)
#pragma unroll
    for (int fj = 0; fj < 4; ++fj)
#pragma unroll
      for (int r = 0; r < 4; ++r)
        red[(16 * fi + q4 + r) * 64 + 16 * fj + m16] = acc[fi][fj][r];
  __syncthreads();

  float* Jp = ws + 4096 + (size_t)((chunk & jmask) * NB + b) * 4096;
  for (int i = t; i < 4096; i += 128)
    atomicAdd(&Jp[i], smem[i] + smem[8192 + i]);
  for (int i = t; i < 192; i += 128)
    atomicAdd(&ws[(i >> 6) * 1024 + b * 64 + (i & 63)], sbuf[0][i] + sbuf[1][i]);
}

__global__ __launch_bounds__(256) void mi_gw_kernel(const float* __restrict__ ws,
                                                    float* __restrict__ gw,
                                                    int npart) {
  const int b = blockIdx.x, t = threadIdx.x;
  __shared__ float sSv[64], sSt[64];
  if (t < 64) sSv[t] = ws[b * 64 + t];
  else if (t < 128) sSt[t - 64] = ws[1024 + b * 64 + (t - 64)];
  __syncthreads();

  // thread t owns J elements [16t,16t+16): row c = t>>2, cols d = (t&3)*16+[0,16)
  f32x4 jr0 = {0,0,0,0}, jr1 = {0,0,0,0}, jr2 = {0,0,0,0}, jr3 = {0,0,0,0};
  const float* base = ws + 4096 + (size_t)b * 4096 + t * 16;
  for (int p = 0; p < npart; ++p) {
    const f32x4* cp = (const f32x4*)(base + (size_t)p * (NB * 4096));
    jr0 += cp[0]; jr1 += cp[1]; jr2 += cp[2]; jr3 += cp[3];
  }

  const float HW2 = (float)HW * (float)HW;
  const float fv = HW2 / sSv[t >> 2];
  const int d0 = (t & 3) * 16;
  float part = 0.f;
#pragma unroll
  for (int j = 0; j < 16; ++j) {
    float jv = (j < 4) ? jr0[j] : (j < 8) ? jr1[j - 4] : (j < 12) ? jr2[j - 8] : jr3[j - 12];
    float q = jv * (fv / sSt[d0 + j]);
    part += q * __logf(q + 1e-9f);
  }
  part = wave_reduce_sum(part);
  __shared__ float sh[4];
  __shared__ float mi_sh;
  int wid = t >> 6, lane = t & 63;
  if (lane == 0) sh[wid] = part;
  __syncthreads();
  if (t == 0) mi_sh = ((sh[0] + sh[1]) + (sh[2] + sh[3])) / HW2;
  __syncthreads();
  if (t < 64) {
    float S = sSt[t];
    float U = ws[2048 + b * 64 + t];
    float ent = __logf(S) - U / S;               // text spatial entropy
    float z = 1.0f - ent + 0.5f * mi_sh;
    gw[b * 64 + t] = 1.0f / (1.0f + __expf(-z));
  }
}

__global__ __launch_bounds__(256) void enhance_kernel(const float4* __restrict__ vis,
                                                      const float4* __restrict__ text,
                                                      const float* __restrict__ gw,
                                                      float4* __restrict__ out) {
  const size_t total4 = (size_t)NB * NC * HW / 4;   // 4194304
  for (size_t i = (size_t)blockIdx.x * 256 + threadIdx.x; i < total4;
       i += (size_t)gridDim.x * 256) {
    float4 v = vis[i];
    float4 t = text[i];
    float g = gw[i >> 12];              // 4096 float4 per (b,c) row
    out[i] = make_float4(v.x + g * t.x, v.y + g * t.y,
                         v.z + g * t.z, v.w + g * t.w);
  }
}

extern "C" void kernel_launch(void* const* d_in, const int* in_sizes, int n_in,
                              void* d_out, int out_size, void* d_ws, size_t ws_size,
                              hipStream_t stream) {
  const float* vis  = (const float*)d_in[0];
  const float* text = (const float*)d_in[1];
  float* out = (float*)d_out;
  float* ws  = (float*)d_ws;
  float* gw  = ws + 3072;

  // npart J partial copies, chosen deterministically from scratch size
  size_t ws_floats = ws_size / sizeof(float);
  int npart = 1;
  if      (ws_floats >= 4096 + 4 * 65536) npart = 4;
  else if (ws_floats >= 4096 + 2 * 65536) npart = 2;

  hipMemsetAsync(ws, 0, (4096 + (size_t)npart * 65536) * sizeof(float), stream);

  joint_db<<<NB * CH, 128, 0, stream>>>(vis, text, ws, npart - 1);
  mi_gw_kernel<<<NB, 256, 0, stream>>>(ws, gw, npart);
  enhance_kernel<<<2048, 256, 0, stream>>>((const float4*)vis, (const float4*)text,
                                           gw, (float4*)out);
}